// Round 9
// baseline (187.986 us; speedup 1.0000x reference)
//
#include <hip/hip_runtime.h>

// Performer causal linear attention, MI355X. Round 9:
//  - fused: 24 independent loads in flight at entry (aQ + E tc0 + S ec0),
//    float4 V staging, __launch_bounds__(256,4)
//  - feat: register preload of next P quarter during current MFMAs
// b=2 h=8 n=4096 d=64 r=256 e=64, chunk=64.

typedef unsigned short ushort_t;
typedef __attribute__((ext_vector_type(8))) short bf16x8;
typedef __attribute__((ext_vector_type(4))) float f32x4;

#define KEPS 1e-4f
#define AEPS 1e-6f
#define NORMIZER 0.35355339059327373f   // 64^-0.25
#define RATIO 0.0625f                   // 256^-0.5

__device__ __forceinline__ ushort_t bf16r(float f) {   // RNE
  unsigned u = __float_as_uint(f);
  return (ushort_t)((u + 0x7fffu + ((u >> 16) & 1u)) >> 16);
}
__device__ __forceinline__ float ubf(ushort_t h) {
  return __uint_as_float((unsigned)h << 16);
}

// ---------------------------------------------------------------------------
// K0: split P into bf16 hi/lo.
__global__ __launch_bounds__(256) void pconv_kernel(
    const float* __restrict__ P, ushort_t* __restrict__ Phi,
    ushort_t* __restrict__ Plo)
{
  int idx = blockIdx.x * 1024 + threadIdx.x;
  #pragma unroll
  for (int p = 0; p < 4; ++p) {
    int i = idx + p * 256;
    float x = P[i];
    ushort_t h = bf16r(x);
    Phi[i] = h;
    Plo[i] = bf16r(x - ubf(h));
  }
}

// ---------------------------------------------------------------------------
// K1: feature map via MFMA. blocks 0..1023 -> q, 1024..2047 -> k.
// P quarters staged in LDS via register preload (latency hidden behind MFMAs).
__global__ __launch_bounds__(256, 4) void feat_mfma(
    const float* __restrict__ Q, const float* __restrict__ K,
    const ushort_t* __restrict__ Phi, const ushort_t* __restrict__ Plo,
    ushort_t* __restrict__ qp, ushort_t* __restrict__ E,
    float* __restrict__ bmax)
{
  __shared__ union {
    struct { ushort_t Xhi[64 * 72]; ushort_t Xlo[64 * 72]; } s;  // 18432 B
    ushort_t outb[64 * 72];   // epilogue staging, aliases Xhi (dead by then)
  } u;
  __shared__ ushort_t Pq[2][64 * 72];   // [hi/lo][col*72 + k], 18432 B
  __shared__ float diagS[64];
  __shared__ float redm[4];

  int bid = blockIdx.x, tid = threadIdx.x;
  bool isK = bid >= 1024;
  const float* X = isK ? K : Q;
  size_t rowbase = (size_t)(isK ? bid - 1024 : bid) * 64;

  // preload P quarter 0 into regs (independent of everything else)
  int pf = tid, pcl = pf >> 3, pk8 = (pf & 7) * 8;
  int pf2 = tid + 256, pcl2 = pf2 >> 3, pk82 = (pf2 & 7) * 8;
  bf16x8 ph0 = *(const bf16x8*)&Phi[(size_t)pcl * 64 + pk8];
  bf16x8 pl0 = *(const bf16x8*)&Plo[(size_t)pcl * 64 + pk8];
  bf16x8 ph1 = *(const bf16x8*)&Phi[(size_t)pcl2 * 64 + pk82];
  bf16x8 pl1 = *(const bf16x8*)&Plo[(size_t)pcl2 * 64 + pk82];

  // stage X -> hi/lo bf16; diag via 16-lane shuffle reduce on fp32 regs
  #pragma unroll
  for (int p = 0; p < 4; ++p) {
    int idx = tid + p * 256;
    int row = idx >> 4, c4 = idx & 15;
    float4 x = *(const float4*)&X[(rowbase + row) * 64 + c4 * 4];
    ushort4 h, l;
    h.x = bf16r(x.x); l.x = bf16r(x.x - ubf(h.x));
    h.y = bf16r(x.y); l.y = bf16r(x.y - ubf(h.y));
    h.z = bf16r(x.z); l.z = bf16r(x.z - ubf(h.z));
    h.w = bf16r(x.w); l.w = bf16r(x.w - ubf(h.w));
    *(ushort4*)&u.s.Xhi[row * 72 + c4 * 4] = h;
    *(ushort4*)&u.s.Xlo[row * 72 + c4 * 4] = l;
    float ss = x.x * x.x + x.y * x.y + x.z * x.z + x.w * x.w;
    ss += __shfl_xor(ss, 1, 64); ss += __shfl_xor(ss, 2, 64);
    ss += __shfl_xor(ss, 4, 64); ss += __shfl_xor(ss, 8, 64);
    if ((tid & 15) == 0) diagS[row] = 0.0625f * ss;
  }
  __syncthreads();

  int lane = tid & 63, wv = tid >> 6;
  int n15 = lane & 15, quad = lane >> 4;

  // A-fragments (hi/lo) from X LDS
  bf16x8 ah[2], al[2];
  #pragma unroll
  for (int ks = 0; ks < 2; ++ks) {
    int off = (16 * wv + n15) * 72 + quad * 8 + 32 * ks;
    ah[ks] = *(const bf16x8*)&u.s.Xhi[off];
    al[ks] = *(const bf16x8*)&u.s.Xlo[off];
  }

  f32x4 acc[16];
  #pragma unroll
  for (int tc = 0; tc < 16; ++tc) acc[tc] = f32x4{0.f, 0.f, 0.f, 0.f};

  #pragma unroll
  for (int q4 = 0; q4 < 4; ++q4) {
    if (q4) __syncthreads();   // prev-quarter MFMA reads done before overwrite
    // write current quarter from regs
    *(bf16x8*)&Pq[0][pcl * 72 + pk8]   = ph0;
    *(bf16x8*)&Pq[1][pcl * 72 + pk8]   = pl0;
    *(bf16x8*)&Pq[0][pcl2 * 72 + pk82] = ph1;
    *(bf16x8*)&Pq[1][pcl2 * 72 + pk82] = pl1;
    // issue next quarter's loads (complete during this quarter's MFMAs)
    if (q4 < 3) {
      size_t g1 = (size_t)((q4 + 1) * 64 + pcl) * 64 + pk8;
      size_t g2 = (size_t)((q4 + 1) * 64 + pcl2) * 64 + pk82;
      ph0 = *(const bf16x8*)&Phi[g1];
      pl0 = *(const bf16x8*)&Plo[g1];
      ph1 = *(const bf16x8*)&Phi[g2];
      pl1 = *(const bf16x8*)&Plo[g2];
    }
    __syncthreads();
    #pragma unroll
    for (int tcl = 0; tcl < 4; ++tcl) {
      f32x4 a = acc[q4 * 4 + tcl];
      #pragma unroll
      for (int ks = 0; ks < 2; ++ks) {
        int off = (16 * tcl + n15) * 72 + quad * 8 + 32 * ks;
        bf16x8 bh = *(const bf16x8*)&Pq[0][off];
        bf16x8 bl = *(const bf16x8*)&Pq[1][off];
        a = __builtin_amdgcn_mfma_f32_16x16x32_bf16(ah[ks], bh, a, 0, 0, 0);
        a = __builtin_amdgcn_mfma_f32_16x16x32_bf16(ah[ks], bl, a, 0, 0, 0);
        a = __builtin_amdgcn_mfma_f32_16x16x32_bf16(al[ks], bh, a, 0, 0, 0);
      }
      acc[q4 * 4 + tcl] = a;
    }
  }

  // C/D: row = 16*wv + quad*4 + r, col = 16*tc + n15
  float dg[4];
  #pragma unroll
  for (int r = 0; r < 4; ++r) dg[r] = diagS[16 * wv + quad * 4 + r];

  float sub[4];
  if (!isK) {
    #pragma unroll
    for (int r = 0; r < 4; ++r) {
      float mx = -3.0e38f;
      #pragma unroll
      for (int tc = 0; tc < 16; ++tc) mx = fmaxf(mx, acc[tc][r]);
      #pragma unroll
      for (int s = 1; s < 16; s <<= 1) mx = fmaxf(mx, __shfl_xor(mx, s, 64));
      sub[r] = dg[r] + NORMIZER * mx;
    }
  } else {
    float bm = -3.0e38f;
    #pragma unroll
    for (int tc = 0; tc < 16; ++tc)
      #pragma unroll
      for (int r = 0; r < 4; ++r) bm = fmaxf(bm, acc[tc][r]);
    #pragma unroll
    for (int s = 1; s < 64; s <<= 1) bm = fmaxf(bm, __shfl_xor(bm, s, 64));
    if (lane == 0) redm[wv] = bm;
    #pragma unroll
    for (int r = 0; r < 4; ++r) sub[r] = dg[r];
  }

  // per-quarter epilogue through LDS (outb aliases dead X tile)
  ushort_t* dst = (isK ? E : qp) + rowbase * 256;
  #pragma unroll
  for (int qt = 0; qt < 4; ++qt) {
    __syncthreads();
    #pragma unroll
    for (int t4 = 0; t4 < 4; ++t4) {
      int tc = qt * 4 + t4;
      #pragma unroll
      for (int r = 0; r < 4; ++r) {
        int row = 16 * wv + quad * 4 + r;
        float ex = __expf(NORMIZER * acc[tc][r] - sub[r]);
        float val = isK ? ex : RATIO * (ex + KEPS);
        u.outb[row * 72 + t4 * 16 + n15] = bf16r(val);
      }
    }
    __syncthreads();
    int row = tid >> 2, c0 = (tid & 3) * 16;
    bf16x8 v0 = *(const bf16x8*)&u.outb[row * 72 + c0];
    bf16x8 v1 = *(const bf16x8*)&u.outb[row * 72 + c0 + 8];
    *(bf16x8*)&dst[row * 256 + qt * 64 + c0] = v0;
    *(bf16x8*)&dst[row * 256 + qt * 64 + c0 + 8] = v1;
  }

  if (isK && tid == 0) {
    float m4 = fmaxf(fmaxf(redm[0], redm[1]), fmaxf(redm[2], redm[3]));
    bmax[bid - 1024] = NORMIZER * m4;
  }
}

// ---------------------------------------------------------------------------
// K1b: reduce 1024 per-block maxes -> kmax (single block).
__global__ __launch_bounds__(256) void kmax_reduce(
    const float* __restrict__ bmax, float* __restrict__ kmax)
{
  __shared__ float red[4];
  int tid = threadIdx.x;
  float m = fmaxf(fmaxf(bmax[tid], bmax[tid + 256]),
                  fmaxf(bmax[tid + 512], bmax[tid + 768]));
  #pragma unroll
  for (int s = 1; s < 64; s <<= 1) m = fmaxf(m, __shfl_xor(m, s, 64));
  if ((tid & 63) == 0) red[tid >> 6] = m;
  __syncthreads();
  if (tid == 0)
    *kmax = fmaxf(fmaxf(red[0], red[1]), fmaxf(red[2], red[3]));
}

// ---------------------------------------------------------------------------
// K2: per-chunk sums via MFMA, kmax-independent.
__global__ __launch_bounds__(256) void chunksum_mfma(
    const ushort_t* __restrict__ E, const float* __restrict__ V,
    ushort_t* __restrict__ SE, float* __restrict__ zE, float* __restrict__ SV)
{
  __shared__ ushort_t Et[256 * 72];
  __shared__ ushort_t Vt[64 * 72];
  __shared__ float red2[256];

  int bc = blockIdx.x, tid = threadIdx.x;
  size_t ebase = (size_t)bc * 16384;

  #pragma unroll
  for (int p = 0; p < 8; ++p) {
    int g = (tid + p * 256) * 8;
    int pos = g >> 8, j0 = g & 255;
    bf16x8 ev = *(const bf16x8*)&E[ebase + g];
    #pragma unroll
    for (int jj = 0; jj < 8; ++jj) {
      int j = j0 + jj;
      int pr = (pos + 8 * ((j >> 3) & 7)) & 63;
      Et[j * 72 + pr] = (ushort_t)ev[jj];
    }
  }
  float vsum = 0.f;
  #pragma unroll
  for (int p = 0; p < 16; ++p) {
    int g = tid + p * 256;
    int pos = g >> 6, e = g & 63;
    float x = V[(size_t)bc * 4096 + g];
    vsum += x;
    int pr = (pos + 8 * ((e >> 3) & 7)) & 63;
    Vt[e * 72 + pr] = bf16r(x);
  }
  red2[tid] = vsum;
  __syncthreads();
  if (tid < 64)
    SV[(size_t)bc * 64 + tid] =
        red2[tid] + red2[64 + tid] + red2[128 + tid] + red2[192 + tid];

  {
    float s = 0.f;
    #pragma unroll
    for (int m8 = 0; m8 < 8; ++m8) {
      bf16x8 r8 = *(const bf16x8*)&Et[tid * 72 + m8 * 8];
      #pragma unroll
      for (int x = 0; x < 8; ++x) s += ubf((ushort_t)r8[x]);
    }
    zE[(size_t)bc * 256 + tid] = s;
  }

  int lane = tid & 63, wv = tid >> 6;
  int n15 = lane & 15, quad = lane >> 4;

  bf16x8 aV[2];
  {
    int e = 16 * wv + n15;
    int rot = 8 * ((e >> 3) & 7);
    #pragma unroll
    for (int ks = 0; ks < 2; ++ks) {
      int pr = (quad * 8 + 32 * ks + rot) & 63;
      aV[ks] = *(const bf16x8*)&Vt[e * 72 + pr];
    }
  }

  f32x4 acc[16];
  #pragma unroll
  for (int tc = 0; tc < 16; ++tc) {
    int j = 16 * tc + n15;
    int rot = 8 * ((j >> 3) & 7);
    f32x4 a = {0.f, 0.f, 0.f, 0.f};
    #pragma unroll
    for (int ks = 0; ks < 2; ++ks) {
      int pr = (quad * 8 + 32 * ks + rot) & 63;
      bf16x8 b = *(const bf16x8*)&Et[j * 72 + pr];
      a = __builtin_amdgcn_mfma_f32_16x16x32_bf16(aV[ks], b, a, 0, 0, 0);
    }
    acc[tc] = a;
  }
  __syncthreads();

  ushort_t* outS = Et;
  #pragma unroll
  for (int tc = 0; tc < 16; ++tc)
    #pragma unroll
    for (int r = 0; r < 4; ++r) {
      int e = 16 * wv + quad * 4 + r;
      outS[e * 264 + 16 * tc + n15] = bf16r(acc[tc][r]);
    }
  __syncthreads();
  #pragma unroll
  for (int p = 0; p < 8; ++p) {
    int g = (tid + p * 256) * 8;
    int e = g >> 8, j0 = g & 255;
    bf16x8 vv = *(const bf16x8*)&outS[e * 264 + j0];
    *(bf16x8*)&SE[ebase + g] = vv;
  }
}

// ---------------------------------------------------------------------------
// K3: exclusive prefix over 64 chunks per bh, applying kp affine correction.
__global__ __launch_bounds__(256) void prefix_kernel(
    ushort_t* __restrict__ S, float* __restrict__ zE,
    const float* __restrict__ SV, const float* __restrict__ kmax)
{
  int b = blockIdx.x;
  float m = *kmax;
  float c1 = RATIO * __expf(-m);
  const float c0 = RATIO * KEPS;
  if (b < 1024) {
    int flat = b * 256 + threadIdx.x;
    int bh = flat >> 14;
    int idx = flat & 16383;
    int e = idx >> 8;
    size_t base = (size_t)bh * 1048576 + idx;
    const float* svp = SV + (size_t)bh * 4096 + e;
    float runE = 0.f, runV = 0.f;
    for (int cc = 0; cc < 64; cc += 8) {
      ushort_t t[8]; float sv[8];
      #pragma unroll
      for (int u2 = 0; u2 < 8; ++u2) {
        t[u2] = S[base + (size_t)(cc + u2) * 16384];
        sv[u2] = svp[(size_t)(cc + u2) * 64];
      }
      #pragma unroll
      for (int u2 = 0; u2 < 8; ++u2) {
        S[base + (size_t)(cc + u2) * 16384] = bf16r(c1 * runE + c0 * runV);
        runE += ubf(t[u2]);
        runV += sv[u2];
      }
    }
  } else {
    int bh = b - 1024;
    int j = threadIdx.x;
    size_t base = (size_t)bh * 16384 + j;
    float run = 0.f;
    for (int cc = 0; cc < 64; cc += 8) {
      float t[8];
      #pragma unroll
      for (int u2 = 0; u2 < 8; ++u2)
        t[u2] = zE[base + (size_t)(cc + u2) * 256];
      #pragma unroll
      for (int u2 = 0; u2 < 8; ++u2) {
        zE[base + (size_t)(cc + u2) * 256] = run;
        run += c1 * t[u2] + 64.0f * c0;
      }
    }
  }
}

// ---------------------------------------------------------------------------
// K4: fused MFMA scores + denominator + output.
// 24 independent loads (aQ, E tc0, S ec0) issued at entry.
__global__ __launch_bounds__(256, 4) void fused_mfma(
    const ushort_t* __restrict__ qp, const ushort_t* __restrict__ E,
    const float* __restrict__ kmax, const float* __restrict__ Z,
    const ushort_t* __restrict__ S, const float* __restrict__ V,
    float* __restrict__ out)
{
  __shared__ ushort_t As[64 * 72];
  __shared__ ushort_t Vt[64 * 72];
  __shared__ float zv[256];
  __shared__ float qsumS[64];
  __shared__ float dqS[64];

  int bc = blockIdx.x, tid = threadIdx.x;
  int lane = tid & 63, wv = tid >> 6;
  int n15 = lane & 15, quad = lane >> 4;
  size_t base = (size_t)bc * 16384;

  // ---- issue all independent loads first ----
  bf16x8 aQ[8];
  #pragma unroll
  for (int ks = 0; ks < 8; ++ks)
    aQ[ks] = *(const bf16x8*)&qp[base + (size_t)(16 * wv + n15) * 256 + quad * 8 + 32 * ks];

  bf16x8 ecur[8], enxt[8];
  #pragma unroll
  for (int ks = 0; ks < 8; ++ks)
    ecur[ks] = *(const bf16x8*)&E[base + (size_t)n15 * 256 + quad * 8 + 32 * ks];

  bf16x8 scur[8], snxt[8];
  #pragma unroll
  for (int ks = 0; ks < 8; ++ks)
    scur[ks] = *(const bf16x8*)&S[base + (size_t)n15 * 256 + quad * 8 + 32 * ks];

  float m = *kmax;
  float c1 = RATIO * __expf(-m);
  const float c0 = RATIO * KEPS;

  zv[tid] = Z[(size_t)bc * 256 + tid] + AEPS;
  // V staging: 4 x float4 coalesced reads, scalar bf16 scatter to Vt
  #pragma unroll
  for (int p = 0; p < 4; ++p) {
    int i4 = p * 1024 + tid * 4;
    float4 x = *(const float4*)&V[(size_t)bc * 4096 + i4];
    int t = i4 >> 6, e0 = i4 & 63;
    Vt[(e0 + 0) * 72 + t] = bf16r(x.x);
    Vt[(e0 + 1) * 72 + t] = bf16r(x.y);
    Vt[(e0 + 2) * 72 + t] = bf16r(x.z);
    Vt[(e0 + 3) * 72 + t] = bf16r(x.w);
  }
  __syncthreads();

  float qsum = 0.f, dq = 0.f;
  #pragma unroll
  for (int ks = 0; ks < 8; ++ks)
    #pragma unroll
    for (int j = 0; j < 8; ++j) {
      float qv = ubf((ushort_t)aQ[ks][j]);
      qsum += qv;
      dq += qv * zv[quad * 8 + 32 * ks + j];
    }
  qsum += __shfl_xor(qsum, 16, 64); qsum += __shfl_xor(qsum, 32, 64);
  dq   += __shfl_xor(dq, 16, 64);   dq   += __shfl_xor(dq, 32, 64);
  if (quad == 0) { qsumS[16 * wv + n15] = qsum; dqS[16 * wv + n15] = dq; }

  // ---- phase A: G = Qp * E^T, depth-1 prefetch ----
  float rs[4] = {0.f, 0.f, 0.f, 0.f};
  #pragma unroll
  for (int tc = 0; tc < 4; ++tc) {
    if (tc < 3) {
      #pragma unroll
      for (int ks = 0; ks < 8; ++ks)
        enxt[ks] = *(const bf16x8*)&E[base + (size_t)(16 * (tc + 1) + n15) * 256 + quad * 8 + 32 * ks];
    }
    f32x4 g = {0.f, 0.f, 0.f, 0.f};
    #pragma unroll
    for (int ks = 0; ks < 8; ++ks)
      g = __builtin_amdgcn_mfma_f32_16x16x32_bf16(aQ[ks], ecur[ks], g, 0, 0, 0);
    #pragma unroll
    for (int r = 0; r < 4; ++r) {
      int i = 16 * wv + quad * 4 + r;
      int t = 16 * tc + n15;
      float val = (t <= i) ? (c1 * g[r] + c0 * qsumS[i]) : 0.f;
      As[i * 72 + t] = bf16r(val);
      rs[r] += val;
    }
    #pragma unroll
    for (int ks = 0; ks < 8; ++ks) ecur[ks] = enxt[ks];
  }

  float dinv[4];
  #pragma unroll
  for (int r = 0; r < 4; ++r) {
    float v = rs[r];
    #pragma unroll
    for (int s = 1; s < 16; s <<= 1) v += __shfl_xor(v, s, 64);
    int i = 16 * wv + quad * 4 + r;
    dinv[r] = 1.f / (dqS[i] + v);
  }

  // ---- phase C: out = [Qp | A_sc] * [Sp ; Vt], depth-1 prefetch on S ----
  #pragma unroll
  for (int ec = 0; ec < 4; ++ec) {
    if (ec < 3) {
      #pragma unroll
      for (int ks = 0; ks < 8; ++ks)
        snxt[ks] = *(const bf16x8*)&S[base + (size_t)(16 * (ec + 1) + n15) * 256 + quad * 8 + 32 * ks];
    }
    f32x4 o = {0.f, 0.f, 0.f, 0.f};
    #pragma unroll
    for (int ks = 0; ks < 8; ++ks)
      o = __builtin_amdgcn_mfma_f32_16x16x32_bf16(aQ[ks], scur[ks], o, 0, 0, 0);
    #pragma unroll
    for (int ks = 0; ks < 2; ++ks) {
      bf16x8 a2 = *(const bf16x8*)&As[(16 * wv + n15) * 72 + quad * 8 + 32 * ks];
      bf16x8 b2 = *(const bf16x8*)&Vt[(16 * ec + n15) * 72 + quad * 8 + 32 * ks];
      o = __builtin_amdgcn_mfma_f32_16x16x32_bf16(a2, b2, o, 0, 0, 0);
    }
    #pragma unroll
    for (int r = 0; r < 4; ++r) {
      int i = 16 * wv + quad * 4 + r;
      out[(size_t)bc * 4096 + (size_t)i * 64 + 16 * ec + n15] = o[r] * dinv[r];
    }
    #pragma unroll
    for (int ks = 0; ks < 8; ++ks) scur[ks] = snxt[ks];
  }
}

// ---------------------------------------------------------------------------
extern "C" void kernel_launch(void* const* d_in, const int* in_sizes, int n_in,
                              void* d_out, int out_size, void* d_ws, size_t ws_size,
                              hipStream_t stream)
{
  const float* q = (const float*)d_in[0];
  const float* k = (const float*)d_in[1];
  const float* v = (const float*)d_in[2];
  const float* P = (const float*)d_in[3];
  float* out = (float*)d_out;

  ushort_t* qp  = (ushort_t*)d_ws;
  ushort_t* E   = qp + 16777216;
  ushort_t* S   = E + 16777216;                 // SE then combined in place
  float*    zE  = (float*)(S + 16777216);       // 262144 floats
  float*    SV  = zE + 262144;                  // 65536 floats
  ushort_t* Phi = (ushort_t*)(SV + 65536);
  ushort_t* Plo = Phi + 16384;
  float*    bmax = (float*)(Plo + 16384);       // 1024 floats
  float*    kmax = bmax + 1024;

  pconv_kernel<<<16, 256, 0, stream>>>(P, Phi, Plo);
  feat_mfma<<<2048, 256, 0, stream>>>(q, k, Phi, Plo, qp, E, bmax);
  kmax_reduce<<<1, 256, 0, stream>>>(bmax, kmax);
  chunksum_mfma<<<1024, 256, 0, stream>>>(E, v, S, zE, SV);
  prefix_kernel<<<1040, 256, 0, stream>>>(S, zE, SV, kmax);
  fused_mfma<<<1024, 256, 0, stream>>>(qp, E, kmax, zE, S, v, out);
}